// Round 2
// baseline (1152.157 us; speedup 1.0000x reference)
//
#include <hip/hip_runtime.h>
#include <hip/hip_bf16.h>
#include <math.h>

#define D_DIM 1024
#define T_DIM 2048
#define B_DIM 8
#define M_DIM (B_DIM * T_DIM)          // 16384
#define SZ ((size_t)M_DIM * D_DIM)     // 16777216
#define NW 11
#define CCH 16                          // scan chunks
#define LCH 128                         // scan chunk length
#define GCH 32                          // grn chunks
#define GLCH 64                         // grn chunk length

typedef __bf16 bf16_t;
typedef __bf16 bf16x8 __attribute__((ext_vector_type(8)));
typedef __bf16 bf16x4 __attribute__((ext_vector_type(4)));
typedef float f32x4 __attribute__((ext_vector_type(4)));

typedef const __attribute__((address_space(1))) void* as1_const_ptr;
typedef __attribute__((address_space(3))) void* as3_ptr;

__device__ __forceinline__ void load_lds_16(const void* g, void* l) {
    __builtin_amdgcn_global_load_lds((as1_const_ptr)g, (as3_ptr)l, 16, 0, 0);
}

__device__ __forceinline__ float sigmoid_f(float x) { return 1.f / (1.f + expf(-x)); }

// ---------------------------------------------------------------------------
// GEMM: C[M,N] = epilogue(A[M,K] @ W[K,N]) with W pre-transposed as Bt[N,K] bf16.
// ACT: 0 none, 1 sigmoid, 2 relu^2.  CMODE: 0 store, 1 C=acc*other,
// 2 C=C+acc*other, 3 C=acc+other (residual; other may alias Cout).
// 128x128 tile, BK=32, 256 thr (4 waves 2x2, each 64x64 via 4x4 mfma 16x16x32).
// ---------------------------------------------------------------------------
template<int ACT, int CMODE, bool OUT_BF16, bool OTHER_BF16>
__global__ void __launch_bounds__(256)
gemm_kernel(const bf16_t* __restrict__ A, const bf16_t* __restrict__ Bt,
            void* Cout, const float* __restrict__ bias, const void* other)
{
    constexpr int K = D_DIM, N = D_DIM;
    __shared__ bf16_t sA[128 * 32];
    __shared__ bf16_t sB[128 * 32];
    const int tid  = threadIdx.x;
    const int wave = tid >> 6, lane = tid & 63;
    const int m0 = blockIdx.y * 128, n0 = blockIdx.x * 128;
    const int wm = (wave & 1) * 64, wn = (wave >> 1) * 64;

    // staging: each wave covers 32 rows (2 instrs of 16 rows), lane -> (row, 8-elem chunk)
    const int srow = wave * 32 + (lane >> 2);
    const int scol = (lane & 3) * 8;
    const bf16_t* gA = A  + (size_t)(m0 + srow) * K + scol;
    const bf16_t* gB = Bt + (size_t)(n0 + srow) * K + scol;
    bf16_t* lA = sA + (wave * 32) * 32;
    bf16_t* lB = sB + (wave * 32) * 32;

    f32x4 acc[4][4] = {};

    const int fr = lane & 15;
    const int q8 = (lane >> 4) * 8;

    for (int kk = 0; kk < K; kk += 32) {
        __syncthreads();
        load_lds_16(gA + kk,                    lA);
        load_lds_16(gA + (size_t)16 * K + kk,   lA + 16 * 32);
        load_lds_16(gB + kk,                    lB);
        load_lds_16(gB + (size_t)16 * K + kk,   lB + 16 * 32);
        __syncthreads();
        bf16x8 af[4], bq[4];
        #pragma unroll
        for (int i = 0; i < 4; i++)
            af[i] = *(const bf16x8*)(sA + (wm + i * 16 + fr) * 32 + q8);
        #pragma unroll
        for (int j = 0; j < 4; j++)
            bq[j] = *(const bf16x8*)(sB + (wn + j * 16 + fr) * 32 + q8);
        #pragma unroll
        for (int i = 0; i < 4; i++)
            #pragma unroll
            for (int j = 0; j < 4; j++)
                acc[i][j] = __builtin_amdgcn_mfma_f32_16x16x32_bf16(af[i], bq[j], acc[i][j], 0, 0, 0);
    }

    const int quad = lane >> 4;
    #pragma unroll
    for (int i = 0; i < 4; i++) {
        #pragma unroll
        for (int j = 0; j < 4; j++) {
            const int col = n0 + wn + j * 16 + fr;
            const float bv = (bias != nullptr) ? bias[col] : 0.f;
            #pragma unroll
            for (int r = 0; r < 4; r++) {
                const int row = m0 + wm + i * 16 + quad * 4 + r;
                const size_t idx = (size_t)row * N + col;
                float v = acc[i][j][r] + bv;
                if (ACT == 1)      v = sigmoid_f(v);
                else if (ACT == 2) { v = fmaxf(v, 0.f); v = v * v; }
                float ov = 0.f;
                if (CMODE != 0)
                    ov = OTHER_BF16 ? (float)((const bf16_t*)other)[idx]
                                    : ((const float*)other)[idx];
                if (CMODE == 1)      v = v * ov;
                else if (CMODE == 2) v = ((const float*)Cout)[idx] + v * ov;
                else if (CMODE == 3) v = v + ov;
                if (OUT_BF16) ((bf16_t*)Cout)[idx] = (bf16_t)v;
                else          ((float*)Cout)[idx]  = v;
            }
        }
    }
}

// ---------------------------------------------------------------------------
// Weight transpose + fp32->bf16:  Wt[n][k] = W[k][n]
// ---------------------------------------------------------------------------
struct WList { const float* w[NW]; };

__global__ void __launch_bounds__(256)
transpose_cvt_kernel(WList wl, bf16_t* wt_base)
{
    __shared__ float tile[32][33];
    const float* W = wl.w[blockIdx.z];
    bf16_t* Wt = wt_base + (size_t)blockIdx.z * D_DIM * D_DIM;
    const int bx = blockIdx.x * 32, by = blockIdx.y * 32;
    const int tx = threadIdx.x, ty = threadIdx.y;
    #pragma unroll
    for (int i = 0; i < 32; i += 8)
        tile[ty + i][tx] = W[(size_t)(by + ty + i) * D_DIM + bx + tx];
    __syncthreads();
    #pragma unroll
    for (int i = 0; i < 32; i += 8)
        Wt[(size_t)(bx + ty + i) * D_DIM + by + tx] = (bf16_t)tile[tx][ty + i];
}

// ---------------------------------------------------------------------------
// ew[d] = exp(decay[d])
// ---------------------------------------------------------------------------
__global__ void __launch_bounds__(256)
ew_kernel(const float* __restrict__ decay, float* __restrict__ ew)
{
    const int d = blockIdx.x * 256 + threadIdx.x;
    if (d < D_DIM) ew[d] = expf(decay[d]);
}

// ---------------------------------------------------------------------------
// LN1 of rows t and t-1, xm = 0.5*(xx_t + xx_{t-1}) -> bf16. One block per row.
// ---------------------------------------------------------------------------
__global__ void __launch_bounds__(256)
ln_shift_kernel(const float* __restrict__ x, const float* __restrict__ w,
                const float* __restrict__ bias, bf16_t* __restrict__ xm)
{
    const int row = blockIdx.x;
    const int t = row & (T_DIM - 1);
    const int d0 = threadIdx.x * 4;
    const float* xc = x + (size_t)row * D_DIM;
    f32x4 c = *(const f32x4*)(xc + d0);
    f32x4 p = {0.f, 0.f, 0.f, 0.f};
    if (t > 0) p = *(const f32x4*)(xc - D_DIM + d0);

    float sc = 0.f, qc = 0.f, sp = 0.f, qp = 0.f;
    #pragma unroll
    for (int e = 0; e < 4; e++) {
        sc += c[e]; qc += c[e] * c[e];
        sp += p[e]; qp += p[e] * p[e];
    }
    #pragma unroll
    for (int off = 32; off > 0; off >>= 1) {
        sc += __shfl_down(sc, off); qc += __shfl_down(qc, off);
        sp += __shfl_down(sp, off); qp += __shfl_down(qp, off);
    }
    __shared__ float red[16];
    const int wv = threadIdx.x >> 6, ln = threadIdx.x & 63;
    if (ln == 0) { red[wv] = sc; red[4 + wv] = qc; red[8 + wv] = sp; red[12 + wv] = qp; }
    __syncthreads();
    sc = red[0] + red[1] + red[2] + red[3];
    qc = red[4] + red[5] + red[6] + red[7];
    sp = red[8] + red[9] + red[10] + red[11];
    qp = red[12] + red[13] + red[14] + red[15];

    const float inv = 1.f / (float)D_DIM;
    const float mc = sc * inv, vc = qc * inv - mc * mc, rc = rsqrtf(vc + 1e-5f);
    const float mp = sp * inv, vp = qp * inv - mp * mp, rp = rsqrtf(vp + 1e-5f);

    bf16x4 o;
    #pragma unroll
    for (int e = 0; e < 4; e++) {
        const int d = d0 + e;
        const float wd = w[d], bd = bias[d];
        const float nc = (c[e] - mc) * rc * wd + bd;
        const float np = (t > 0) ? ((p[e] - mp) * rp * wd + bd) : 0.f;
        o[e] = (bf16_t)(0.5f * (nc + np));
    }
    *(bf16x4*)(xm + (size_t)row * D_DIM + d0) = o;
}

// ---------------------------------------------------------------------------
// scan pass 1: local chunk scans (zero init), IN-PLACE u -> states, + carry out
// ---------------------------------------------------------------------------
__global__ void __launch_bounds__(256)
scan1_kernel(float* __restrict__ u, const float* __restrict__ ew,
             float* __restrict__ carry)
{
    const int gid = blockIdx.x * 256 + threadIdx.x;   // (c*B + b)*D + d
    const int d = gid & (D_DIM - 1);
    const int b = (gid >> 10) & (B_DIM - 1);
    const int c = gid >> 13;
    const float w = expf(-ew[d]);
    float s = 0.f;
    const size_t base = ((size_t)b * T_DIM + (size_t)c * LCH) * D_DIM + d;
    #pragma unroll 4
    for (int tl = 0; tl < LCH; tl++) {
        const size_t idx = base + (size_t)tl * D_DIM;
        s = fmaf(s, w, u[idx]);
        u[idx] = s;
    }
    carry[(size_t)(b * CCH + c) * D_DIM + d] = s;
}

// ---------------------------------------------------------------------------
// scan pass 2: combine carries sequentially -> incoming per chunk + final state
// ---------------------------------------------------------------------------
__global__ void __launch_bounds__(256)
scan2_kernel(const float* __restrict__ s0, const float* __restrict__ ew,
             const float* __restrict__ carry, float* __restrict__ inc,
             float* __restrict__ fstate)
{
    const int gid = blockIdx.x * 256 + threadIdx.x;   // b*D + d
    const int d = gid & (D_DIM - 1);
    const int b = gid >> 10;
    const float wL = expf(-(float)LCH * ew[d]);
    float s = s0[gid];
    #pragma unroll
    for (int c = 0; c < CCH; c++) {
        const size_t idx = (size_t)(b * CCH + c) * D_DIM + d;
        inc[idx] = s;
        s = fmaf(s, wL, carry[idx]);
    }
    fstate[gid] = s;
}

// ---------------------------------------------------------------------------
// scan recombine + GroupNorm(32ch) + mixed = sr*ns*g -> bf16
// ---------------------------------------------------------------------------
__global__ void __launch_bounds__(256)
mixed_kernel(const float* __restrict__ st, const float* __restrict__ inc,
             const float* __restrict__ ew, const bf16_t* __restrict__ sr,
             const bf16_t* __restrict__ g, const float* __restrict__ gnw,
             const float* __restrict__ gnb, bf16_t* __restrict__ outp)
{
    const int row = blockIdx.x;                 // b*T + t
    const int b = row >> 11;
    const int t = row & (T_DIM - 1);
    const int c = t >> 7, tl = t & (LCH - 1);
    const int d0 = threadIdx.x * 4;
    const size_t base = (size_t)row * D_DIM + d0;

    f32x4 lv = *(const f32x4*)(st + base);
    f32x4 iv = *(const f32x4*)(inc + (size_t)(b * CCH + c) * D_DIM + d0);
    f32x4 ev = *(const f32x4*)(ew + d0);

    float s[4];
    float sum = 0.f, sq = 0.f;
    #pragma unroll
    for (int e = 0; e < 4; e++) {
        s[e] = lv[e] + expf(-(float)(tl + 1) * ev[e]) * iv[e];
        sum += s[e]; sq += s[e] * s[e];
    }
    // group of 32 channels == 8 consecutive lanes
    #pragma unroll
    for (int m = 1; m <= 4; m <<= 1) { sum += __shfl_xor(sum, m); sq += __shfl_xor(sq, m); }
    const float mean = sum * (1.f / 32.f);
    const float var  = sq * (1.f / 32.f) - mean * mean;
    const float rstd = rsqrtf(var + 1e-5f);

    bf16x4 rv = *(const bf16x4*)(sr + base);
    bf16x4 gv = *(const bf16x4*)(g + base);
    f32x4 wv = *(const f32x4*)(gnw + d0);
    f32x4 bv = *(const f32x4*)(gnb + d0);
    bf16x4 o;
    #pragma unroll
    for (int e = 0; e < 4; e++) {
        const float ns = (s[e] - mean) * rstd * wv[e] + bv[e];
        o[e] = (bf16_t)((float)rv[e] * ns * (float)gv[e]);
    }
    *(bf16x4*)(outp + base) = o;
}

// ---------------------------------------------------------------------------
// LN2: read x2, write normalized bf16
// ---------------------------------------------------------------------------
__global__ void __launch_bounds__(256)
ln2_kernel(const float* __restrict__ x2, const float* __restrict__ w,
           const float* __restrict__ bias, bf16_t* __restrict__ xx2)
{
    const int row = blockIdx.x;
    const int d0 = threadIdx.x * 4;
    const float* xc = x2 + (size_t)row * D_DIM;
    f32x4 c = *(const f32x4*)(xc + d0);
    float sc = 0.f, qc = 0.f;
    #pragma unroll
    for (int e = 0; e < 4; e++) { sc += c[e]; qc += c[e] * c[e]; }
    #pragma unroll
    for (int off = 32; off > 0; off >>= 1) {
        sc += __shfl_down(sc, off); qc += __shfl_down(qc, off);
    }
    __shared__ float red[8];
    const int wv = threadIdx.x >> 6, ln = threadIdx.x & 63;
    if (ln == 0) { red[wv] = sc; red[4 + wv] = qc; }
    __syncthreads();
    sc = red[0] + red[1] + red[2] + red[3];
    qc = red[4] + red[5] + red[6] + red[7];
    const float inv = 1.f / (float)D_DIM;
    const float m = sc * inv, v = qc * inv - m * m, rs = rsqrtf(v + 1e-5f);
    bf16x4 o;
    #pragma unroll
    for (int e = 0; e < 4; e++) {
        const int d = d0 + e;
        o[e] = (bf16_t)((c[e] - m) * rs * w[d] + bias[d]);
    }
    *(bf16x4*)(xx2 + (size_t)row * D_DIM + d0) = o;
}

// ---------------------------------------------------------------------------
// GRN pass 1: partial sum of h^2 over time chunks
// ---------------------------------------------------------------------------
__global__ void __launch_bounds__(256)
grn1_kernel(const float* __restrict__ h, float* __restrict__ partial)
{
    const int blk = blockIdx.x;            // b*GCH + c
    const int b = blk >> 5, c = blk & (GCH - 1);
    const int d0 = threadIdx.x * 4;
    const size_t base = ((size_t)b * T_DIM + (size_t)c * GLCH) * D_DIM + d0;
    f32x4 acc = {0.f, 0.f, 0.f, 0.f};
    for (int tl = 0; tl < GLCH; tl++) {
        f32x4 hv = *(const f32x4*)(h + base + (size_t)tl * D_DIM);
        #pragma unroll
        for (int e = 0; e < 4; e++) acc[e] = fmaf(hv[e], hv[e], acc[e]);
    }
    *(f32x4*)(partial + (size_t)blk * D_DIM + d0) = acc;
}

// ---------------------------------------------------------------------------
// GRN pass 2: gx = sqrt(sum), nx = gx / (mean_d(gx) + 1e-6)
// ---------------------------------------------------------------------------
__global__ void __launch_bounds__(1024)
grn2_kernel(const float* __restrict__ partial, float* __restrict__ nx)
{
    const int b = blockIdx.x, d = threadIdx.x;
    float s = 0.f;
    #pragma unroll 4
    for (int c = 0; c < GCH; c++) s += partial[(size_t)(b * GCH + c) * D_DIM + d];
    const float gx = sqrtf(s);
    float v = gx;
    #pragma unroll
    for (int off = 32; off > 0; off >>= 1) v += __shfl_down(v, off);
    __shared__ float red[16];
    if ((threadIdx.x & 63) == 0) red[threadIdx.x >> 6] = v;
    __syncthreads();
    float tot = 0.f;
    #pragma unroll
    for (int i = 0; i < 16; i++) tot += red[i];
    nx[b * D_DIM + d] = gx / (tot * (1.f / (float)D_DIM) + 1e-6f);
}

// ---------------------------------------------------------------------------
// frh = fr * (gamma*(h*nx) + beta + h) -> bf16
// ---------------------------------------------------------------------------
__global__ void __launch_bounds__(256)
frh_kernel(const float* __restrict__ h, const bf16_t* __restrict__ fr,
           const float* __restrict__ nx, const float* __restrict__ gamma,
           const float* __restrict__ beta, bf16_t* __restrict__ outp)
{
    const size_t gid = (size_t)blockIdx.x * 256 + threadIdx.x;
    const size_t i4 = gid * 4;
    const int d = (int)(i4 & (D_DIM - 1));
    const int b = (int)(i4 >> 21);     // T*D = 2^21
    f32x4 hv = *(const f32x4*)(h + i4);
    bf16x4 fv = *(const bf16x4*)(fr + i4);
    f32x4 nv = *(const f32x4*)(nx + (size_t)b * D_DIM + d);
    f32x4 gm = *(const f32x4*)(gamma + d);
    f32x4 bt = *(const f32x4*)(beta + d);
    bf16x4 o;
    #pragma unroll
    for (int e = 0; e < 4; e++) {
        const float hh = hv[e];
        const float val = gm[e] * (hh * nv[e]) + bt[e] + hh;
        o[e] = (bf16_t)((float)fv[e] * val);
    }
    *(bf16x4*)(outp + i4) = o;
}

// ---------------------------------------------------------------------------
extern "C" void kernel_launch(void* const* d_in, const int* in_sizes, int n_in,
                              void* d_out, int out_size, void* d_ws, size_t ws_size,
                              hipStream_t stream)
{
    (void)in_sizes; (void)n_in; (void)out_size; (void)ws_size;

    const float* x      = (const float*)d_in[0];
    const float* state0 = (const float*)d_in[1];
    const float* ln1_w  = (const float*)d_in[2];
    const float* ln1_b  = (const float*)d_in[3];
    const float* ln2_w  = (const float*)d_in[4];
    const float* ln2_b  = (const float*)d_in[5];
    const float* gn_w   = (const float*)d_in[6];
    const float* gn_b   = (const float*)d_in[7];
    const float* grn_g  = (const float*)d_in[8];
    const float* grn_b  = (const float*)d_in[9];
    const float* decay  = (const float*)d_in[10];
    const float* bfk    = (const float*)d_in[20];
    const float* bfv    = (const float*)d_in[22];
    const float* bfr    = (const float*)d_in[24];

    // workspace layout (~216 MB total)
    const size_t WSZ = (size_t)D_DIM * D_DIM;
    float*  F1 = (float*)d_ws;         // k -> u -> states -> h   (fp32, 64MB)
    bf16_t* B0 = (bf16_t*)(F1 + SZ);   // xm -> xx2               (bf16, 32MB)
    bf16_t* B1 = B0 + SZ;              // a -> mixed -> k_ffn
    bf16_t* B2 = B1 + SZ;              // sr=sigmoid(r) -> fr
    bf16_t* B3 = B2 + SZ;              // g -> frh
    bf16_t* WT = B3 + SZ;              // 11 transposed bf16 weights (22MB)
    float*  carry   = (float*)(WT + NW * WSZ);
    float*  inc     = carry + (size_t)B_DIM * CCH * D_DIM;
    float*  partial = inc + (size_t)B_DIM * CCH * D_DIM;
    float*  nxp     = partial + (size_t)B_DIM * GCH * D_DIM;
    float*  ewp     = nxp + (size_t)B_DIM * D_DIM;

    // weight slots: 0 Wr,1 Wk,2 Wv,3 Wa,4 Wb,5 Wg,6 Wout,7 Wfk,8 Wfv,9 Wfr,10 Wffnout
    WList wl;
    const int widx[NW] = {11, 12, 13, 15, 16, 14, 17, 19, 21, 23, 18};
    for (int i = 0; i < NW; i++) wl.w[i] = (const float*)d_in[widx[i]];

    float* out_x  = (float*)d_out;
    float* out_st = out_x + SZ;

    transpose_cvt_kernel<<<dim3(32, 32, NW), dim3(32, 8), 0, stream>>>(wl, WT);
    ew_kernel<<<4, 256, 0, stream>>>(decay, ewp);
    ln_shift_kernel<<<M_DIM, 256, 0, stream>>>(x, ln1_w, ln1_b, B0);

    const dim3 gg(D_DIM / 128, M_DIM / 128);
    // sr = sigmoid(xm@Wr) [bf16]
    gemm_kernel<1, 0, true,  false><<<gg, 256, 0, stream>>>(B0, WT + 0 * WSZ, B2, nullptr, nullptr);
    // k [fp32]
    gemm_kernel<0, 0, false, false><<<gg, 256, 0, stream>>>(B0, WT + 1 * WSZ, F1, nullptr, nullptr);
    // u = v*k (in-place on F1)
    gemm_kernel<0, 1, false, false><<<gg, 256, 0, stream>>>(B0, WT + 2 * WSZ, F1, nullptr, F1);
    // a [bf16]
    gemm_kernel<0, 0, true,  false><<<gg, 256, 0, stream>>>(B0, WT + 3 * WSZ, B1, nullptr, nullptr);
    // u += b*a
    gemm_kernel<0, 2, false, true ><<<gg, 256, 0, stream>>>(B0, WT + 4 * WSZ, F1, nullptr, B1);
    // g = sigmoid(xm@Wg) [bf16]
    gemm_kernel<1, 0, true,  false><<<gg, 256, 0, stream>>>(B0, WT + 5 * WSZ, B3, nullptr, nullptr);

    scan1_kernel<<<(CCH * B_DIM * D_DIM) / 256, 256, 0, stream>>>(F1, ewp, carry);
    scan2_kernel<<<(B_DIM * D_DIM) / 256, 256, 0, stream>>>(state0, ewp, carry, inc, out_st);
    mixed_kernel<<<M_DIM, 256, 0, stream>>>(F1, inc, ewp, B2, B3, gn_w, gn_b, B1);

    // x2 = x + mixed @ Wout  -> directly into d_out
    gemm_kernel<0, 3, false, false><<<gg, 256, 0, stream>>>(B1, WT + 6 * WSZ, out_x, nullptr, x);
    ln2_kernel<<<M_DIM, 256, 0, stream>>>(out_x, ln2_w, ln2_b, B0);

    // k_ffn = relu^2(xx2@Wfk + bfk) [bf16]; h = k_ffn@Wfv + bfv [fp32];
    // fr = sigmoid(xx2@Wfr + bfr) [bf16]
    gemm_kernel<2, 0, true,  false><<<gg, 256, 0, stream>>>(B0, WT + 7 * WSZ, B1, bfk, nullptr);
    gemm_kernel<0, 0, false, false><<<gg, 256, 0, stream>>>(B1, WT + 8 * WSZ, F1, bfv, nullptr);
    gemm_kernel<1, 0, true,  false><<<gg, 256, 0, stream>>>(B0, WT + 9 * WSZ, B2, bfr, nullptr);

    grn1_kernel<<<B_DIM * GCH, 256, 0, stream>>>(F1, partial);
    grn2_kernel<<<B_DIM, 1024, 0, stream>>>(partial, nxp);
    frh_kernel<<<M_DIM, 256, 0, stream>>>(F1, B2, nxp, grn_g, grn_b, B3);

    // out = x2 + frh @ Wffnout  (in-place accumulate into d_out)
    gemm_kernel<0, 3, false, false><<<gg, 256, 0, stream>>>(B3, WT + 10 * WSZ, out_x, nullptr, out_x);
}

// Round 3
// 1061.901 us; speedup vs baseline: 1.0850x; 1.0850x over previous
//
#include <hip/hip_runtime.h>
#include <hip/hip_bf16.h>
#include <math.h>

#define D_DIM 1024
#define T_DIM 2048
#define B_DIM 8
#define M_DIM (B_DIM * T_DIM)          // 16384
#define SZ ((size_t)M_DIM * D_DIM)     // 16777216
#define NW 11
#define CCH 16                          // scan chunks
#define LCH 128                         // scan chunk length
#define GCH 32                          // grn chunks
#define GLCH 64                         // grn chunk length

typedef __bf16 bf16_t;
typedef __bf16 bf16x8 __attribute__((ext_vector_type(8)));
typedef __bf16 bf16x4 __attribute__((ext_vector_type(4)));
typedef float f32x4 __attribute__((ext_vector_type(4)));

typedef const __attribute__((address_space(1))) void* as1_const_ptr;
typedef __attribute__((address_space(3))) void* as3_ptr;

__device__ __forceinline__ void load_lds_16(const void* g, void* l) {
    __builtin_amdgcn_global_load_lds((as1_const_ptr)g, (as3_ptr)l, 16, 0, 0);
}

__device__ __forceinline__ float sigmoid_f(float x) { return 1.f / (1.f + expf(-x)); }

// ---------------------------------------------------------------------------
// GEMM: C[M,N] = epilogue(A[M,K] @ W[K,N]) with W pre-transposed as Bt[N,K] bf16.
// ACT: 0 none, 1 sigmoid, 2 relu^2.  CMODE: 0 store, 1 C=acc*other,
// 2 C=C+acc*other, 3 C=acc+other (residual; other may alias Cout).
// 128x128 tile, BK=32, 256 thr (4 waves 2x2, each 64x64 via 4x4 mfma 16x16x32).
// LDS chunk XOR-swizzle (chunk ^= (row>>1)&3) kills the 8-way ds_read_b128
// bank conflict while keeping global_load_lds dest contiguous.
// XCD swizzle: xcd = lin&7 owns 16 m-tiles x all 8 n-tiles (A stays in its L2).
// ---------------------------------------------------------------------------
template<int ACT, int CMODE, bool OUT_BF16, bool OTHER_BF16>
__global__ void __launch_bounds__(256)
gemm_kernel(const bf16_t* __restrict__ A, const bf16_t* __restrict__ Bt,
            void* Cout, const float* __restrict__ bias, const void* other)
{
    constexpr int K = D_DIM, N = D_DIM;
    __shared__ bf16_t sA[128 * 32];
    __shared__ bf16_t sB[128 * 32];
    const int tid  = threadIdx.x;
    const int wave = tid >> 6, lane = tid & 63;

    const int lin = blockIdx.x;
    const int xcd = lin & 7;
    const int idx = lin >> 3;               // 0..127
    const int mt  = xcd * 16 + (idx >> 3);  // 0..127
    const int nt  = idx & 7;                // 0..7
    const int m0 = mt * 128, n0 = nt * 128;

    const int wm = (wave & 1) * 64, wn = (wave >> 1) * 64;

    // staging: each wave covers 32 rows (2 instrs of 16 rows).
    // lane -> local row rl = lane>>2 (0..15), chunk c = lane&3 (8 bf16 each).
    // global source chunk is XOR-swizzled so LDS chunk c holds global chunk
    // c ^ ((rl>>1)&3); LDS dest stays base + lane*16 (contiguous).
    const int rl = lane >> 2;
    const int cc = lane & 3;
    const int scol = (cc ^ ((rl >> 1) & 3)) * 8;
    const int srow = wave * 32 + rl;
    const bf16_t* gA = A  + (size_t)(m0 + srow) * K + scol;
    const bf16_t* gB = Bt + (size_t)(n0 + srow) * K + scol;
    bf16_t* lA = sA + (wave * 32) * 32;
    bf16_t* lB = sB + (wave * 32) * 32;

    f32x4 acc[4][4] = {};

    const int fr = lane & 15;
    const int quad = lane >> 4;
    const int qs = (quad ^ ((fr >> 1) & 3)) * 8;   // swizzled fragment chunk

    for (int kk = 0; kk < K; kk += 32) {
        __syncthreads();
        load_lds_16(gA + kk,                    lA);
        load_lds_16(gA + (size_t)16 * K + kk,   lA + 16 * 32);
        load_lds_16(gB + kk,                    lB);
        load_lds_16(gB + (size_t)16 * K + kk,   lB + 16 * 32);
        __syncthreads();
        bf16x8 af[4], bq[4];
        #pragma unroll
        for (int i = 0; i < 4; i++)
            af[i] = *(const bf16x8*)(sA + (wm + i * 16 + fr) * 32 + qs);
        #pragma unroll
        for (int j = 0; j < 4; j++)
            bq[j] = *(const bf16x8*)(sB + (wn + j * 16 + fr) * 32 + qs);
        #pragma unroll
        for (int i = 0; i < 4; i++)
            #pragma unroll
            for (int j = 0; j < 4; j++)
                acc[i][j] = __builtin_amdgcn_mfma_f32_16x16x32_bf16(af[i], bq[j], acc[i][j], 0, 0, 0);
    }

    #pragma unroll
    for (int i = 0; i < 4; i++) {
        #pragma unroll
        for (int j = 0; j < 4; j++) {
            const int col = n0 + wn + j * 16 + fr;
            const float bv = (bias != nullptr) ? bias[col] : 0.f;
            #pragma unroll
            for (int r = 0; r < 4; r++) {
                const int row = m0 + wm + i * 16 + quad * 4 + r;
                const size_t idx2 = (size_t)row * N + col;
                float v = acc[i][j][r] + bv;
                if (ACT == 1)      v = sigmoid_f(v);
                else if (ACT == 2) { v = fmaxf(v, 0.f); v = v * v; }
                float ov = 0.f;
                if (CMODE != 0)
                    ov = OTHER_BF16 ? (float)((const bf16_t*)other)[idx2]
                                    : ((const float*)other)[idx2];
                if (CMODE == 1)      v = v * ov;
                else if (CMODE == 2) v = ((const float*)Cout)[idx2] + v * ov;
                else if (CMODE == 3) v = v + ov;
                if (OUT_BF16) ((bf16_t*)Cout)[idx2] = (bf16_t)v;
                else          ((float*)Cout)[idx2]  = v;
            }
        }
    }
}

// ---------------------------------------------------------------------------
// Weight transpose + fp32->bf16:  Wt[n][k] = W[k][n]
// ---------------------------------------------------------------------------
struct WList { const float* w[NW]; };

__global__ void __launch_bounds__(256)
transpose_cvt_kernel(WList wl, bf16_t* wt_base)
{
    __shared__ float tile[32][33];
    const float* W = wl.w[blockIdx.z];
    bf16_t* Wt = wt_base + (size_t)blockIdx.z * D_DIM * D_DIM;
    const int bx = blockIdx.x * 32, by = blockIdx.y * 32;
    const int tx = threadIdx.x, ty = threadIdx.y;
    #pragma unroll
    for (int i = 0; i < 32; i += 8)
        tile[ty + i][tx] = W[(size_t)(by + ty + i) * D_DIM + bx + tx];
    __syncthreads();
    #pragma unroll
    for (int i = 0; i < 32; i += 8)
        Wt[(size_t)(bx + ty + i) * D_DIM + by + tx] = (bf16_t)tile[tx][ty + i];
}

// ---------------------------------------------------------------------------
// ew[d] = exp(decay[d])
// ---------------------------------------------------------------------------
__global__ void __launch_bounds__(256)
ew_kernel(const float* __restrict__ decay, float* __restrict__ ew)
{
    const int d = blockIdx.x * 256 + threadIdx.x;
    if (d < D_DIM) ew[d] = expf(decay[d]);
}

// ---------------------------------------------------------------------------
// LN1 of rows t and t-1, xm = 0.5*(xx_t + xx_{t-1}) -> bf16. One block per row.
// ---------------------------------------------------------------------------
__global__ void __launch_bounds__(256)
ln_shift_kernel(const float* __restrict__ x, const float* __restrict__ w,
                const float* __restrict__ bias, bf16_t* __restrict__ xm)
{
    const int row = blockIdx.x;
    const int t = row & (T_DIM - 1);
    const int d0 = threadIdx.x * 4;
    const float* xc = x + (size_t)row * D_DIM;
    f32x4 c = *(const f32x4*)(xc + d0);
    f32x4 p = {0.f, 0.f, 0.f, 0.f};
    if (t > 0) p = *(const f32x4*)(xc - D_DIM + d0);

    float sc = 0.f, qc = 0.f, sp = 0.f, qp = 0.f;
    #pragma unroll
    for (int e = 0; e < 4; e++) {
        sc += c[e]; qc += c[e] * c[e];
        sp += p[e]; qp += p[e] * p[e];
    }
    #pragma unroll
    for (int off = 32; off > 0; off >>= 1) {
        sc += __shfl_down(sc, off); qc += __shfl_down(qc, off);
        sp += __shfl_down(sp, off); qp += __shfl_down(qp, off);
    }
    __shared__ float red[16];
    const int wv = threadIdx.x >> 6, ln = threadIdx.x & 63;
    if (ln == 0) { red[wv] = sc; red[4 + wv] = qc; red[8 + wv] = sp; red[12 + wv] = qp; }
    __syncthreads();
    sc = red[0] + red[1] + red[2] + red[3];
    qc = red[4] + red[5] + red[6] + red[7];
    sp = red[8] + red[9] + red[10] + red[11];
    qp = red[12] + red[13] + red[14] + red[15];

    const float inv = 1.f / (float)D_DIM;
    const float mc = sc * inv, vc = qc * inv - mc * mc, rc = rsqrtf(vc + 1e-5f);
    const float mp = sp * inv, vp = qp * inv - mp * mp, rp = rsqrtf(vp + 1e-5f);

    bf16x4 o;
    #pragma unroll
    for (int e = 0; e < 4; e++) {
        const int d = d0 + e;
        const float wd = w[d], bd = bias[d];
        const float nc = (c[e] - mc) * rc * wd + bd;
        const float np = (t > 0) ? ((p[e] - mp) * rp * wd + bd) : 0.f;
        o[e] = (bf16_t)(0.5f * (nc + np));
    }
    *(bf16x4*)(xm + (size_t)row * D_DIM + d0) = o;
}

// ---------------------------------------------------------------------------
// scan pass 1: local chunk scans (zero init), IN-PLACE u -> states, + carry out
// ---------------------------------------------------------------------------
__global__ void __launch_bounds__(256)
scan1_kernel(float* __restrict__ u, const float* __restrict__ ew,
             float* __restrict__ carry)
{
    const int gid = blockIdx.x * 256 + threadIdx.x;   // (c*B + b)*D + d
    const int d = gid & (D_DIM - 1);
    const int b = (gid >> 10) & (B_DIM - 1);
    const int c = gid >> 13;
    const float w = expf(-ew[d]);
    float s = 0.f;
    const size_t base = ((size_t)b * T_DIM + (size_t)c * LCH) * D_DIM + d;
    #pragma unroll 4
    for (int tl = 0; tl < LCH; tl++) {
        const size_t idx = base + (size_t)tl * D_DIM;
        s = fmaf(s, w, u[idx]);
        u[idx] = s;
    }
    carry[(size_t)(b * CCH + c) * D_DIM + d] = s;
}

// ---------------------------------------------------------------------------
// scan pass 2: combine carries sequentially -> incoming per chunk + final state
// ---------------------------------------------------------------------------
__global__ void __launch_bounds__(256)
scan2_kernel(const float* __restrict__ s0, const float* __restrict__ ew,
             const float* __restrict__ carry, float* __restrict__ inc,
             float* __restrict__ fstate)
{
    const int gid = blockIdx.x * 256 + threadIdx.x;   // b*D + d
    const int d = gid & (D_DIM - 1);
    const int b = gid >> 10;
    const float wL = expf(-(float)LCH * ew[d]);
    float s = s0[gid];
    #pragma unroll
    for (int c = 0; c < CCH; c++) {
        const size_t idx = (size_t)(b * CCH + c) * D_DIM + d;
        inc[idx] = s;
        s = fmaf(s, wL, carry[idx]);
    }
    fstate[gid] = s;
}

// ---------------------------------------------------------------------------
// scan recombine + GroupNorm(32ch) + mixed = sr*ns*g -> bf16
// ---------------------------------------------------------------------------
__global__ void __launch_bounds__(256)
mixed_kernel(const float* __restrict__ st, const float* __restrict__ inc,
             const float* __restrict__ ew, const bf16_t* __restrict__ sr,
             const bf16_t* __restrict__ g, const float* __restrict__ gnw,
             const float* __restrict__ gnb, bf16_t* __restrict__ outp)
{
    const int row = blockIdx.x;                 // b*T + t
    const int b = row >> 11;
    const int t = row & (T_DIM - 1);
    const int c = t >> 7, tl = t & (LCH - 1);
    const int d0 = threadIdx.x * 4;
    const size_t base = (size_t)row * D_DIM + d0;

    f32x4 lv = *(const f32x4*)(st + base);
    f32x4 iv = *(const f32x4*)(inc + (size_t)(b * CCH + c) * D_DIM + d0);
    f32x4 ev = *(const f32x4*)(ew + d0);

    float s[4];
    float sum = 0.f, sq = 0.f;
    #pragma unroll
    for (int e = 0; e < 4; e++) {
        s[e] = lv[e] + expf(-(float)(tl + 1) * ev[e]) * iv[e];
        sum += s[e]; sq += s[e] * s[e];
    }
    // group of 32 channels == 8 consecutive lanes
    #pragma unroll
    for (int m = 1; m <= 4; m <<= 1) { sum += __shfl_xor(sum, m); sq += __shfl_xor(sq, m); }
    const float mean = sum * (1.f / 32.f);
    const float var  = sq * (1.f / 32.f) - mean * mean;
    const float rstd = rsqrtf(var + 1e-5f);

    bf16x4 rv = *(const bf16x4*)(sr + base);
    bf16x4 gv = *(const bf16x4*)(g + base);
    f32x4 wv = *(const f32x4*)(gnw + d0);
    f32x4 bv = *(const f32x4*)(gnb + d0);
    bf16x4 o;
    #pragma unroll
    for (int e = 0; e < 4; e++) {
        const float ns = (s[e] - mean) * rstd * wv[e] + bv[e];
        o[e] = (bf16_t)((float)rv[e] * ns * (float)gv[e]);
    }
    *(bf16x4*)(outp + base) = o;
}

// ---------------------------------------------------------------------------
// LN2: read x2, write normalized bf16
// ---------------------------------------------------------------------------
__global__ void __launch_bounds__(256)
ln2_kernel(const float* __restrict__ x2, const float* __restrict__ w,
           const float* __restrict__ bias, bf16_t* __restrict__ xx2)
{
    const int row = blockIdx.x;
    const int d0 = threadIdx.x * 4;
    const float* xc = x2 + (size_t)row * D_DIM;
    f32x4 c = *(const f32x4*)(xc + d0);
    float sc = 0.f, qc = 0.f;
    #pragma unroll
    for (int e = 0; e < 4; e++) { sc += c[e]; qc += c[e] * c[e]; }
    #pragma unroll
    for (int off = 32; off > 0; off >>= 1) {
        sc += __shfl_down(sc, off); qc += __shfl_down(qc, off);
    }
    __shared__ float red[8];
    const int wv = threadIdx.x >> 6, ln = threadIdx.x & 63;
    if (ln == 0) { red[wv] = sc; red[4 + wv] = qc; }
    __syncthreads();
    sc = red[0] + red[1] + red[2] + red[3];
    qc = red[4] + red[5] + red[6] + red[7];
    const float inv = 1.f / (float)D_DIM;
    const float m = sc * inv, v = qc * inv - m * m, rs = rsqrtf(v + 1e-5f);
    bf16x4 o;
    #pragma unroll
    for (int e = 0; e < 4; e++) {
        const int d = d0 + e;
        o[e] = (bf16_t)((c[e] - m) * rs * w[d] + bias[d]);
    }
    *(bf16x4*)(xx2 + (size_t)row * D_DIM + d0) = o;
}

// ---------------------------------------------------------------------------
// GRN pass 1: partial sum of h^2 over time chunks
// ---------------------------------------------------------------------------
__global__ void __launch_bounds__(256)
grn1_kernel(const float* __restrict__ h, float* __restrict__ partial)
{
    const int blk = blockIdx.x;            // b*GCH + c
    const int b = blk >> 5, c = blk & (GCH - 1);
    const int d0 = threadIdx.x * 4;
    const size_t base = ((size_t)b * T_DIM + (size_t)c * GLCH) * D_DIM + d0;
    f32x4 acc = {0.f, 0.f, 0.f, 0.f};
    for (int tl = 0; tl < GLCH; tl++) {
        f32x4 hv = *(const f32x4*)(h + base + (size_t)tl * D_DIM);
        #pragma unroll
        for (int e = 0; e < 4; e++) acc[e] = fmaf(hv[e], hv[e], acc[e]);
    }
    *(f32x4*)(partial + (size_t)blk * D_DIM + d0) = acc;
}

// ---------------------------------------------------------------------------
// GRN pass 2: gx = sqrt(sum), nx = gx / (mean_d(gx) + 1e-6)
// ---------------------------------------------------------------------------
__global__ void __launch_bounds__(1024)
grn2_kernel(const float* __restrict__ partial, float* __restrict__ nx)
{
    const int b = blockIdx.x, d = threadIdx.x;
    float s = 0.f;
    #pragma unroll 4
    for (int c = 0; c < GCH; c++) s += partial[(size_t)(b * GCH + c) * D_DIM + d];
    const float gx = sqrtf(s);
    float v = gx;
    #pragma unroll
    for (int off = 32; off > 0; off >>= 1) v += __shfl_down(v, off);
    __shared__ float red[16];
    if ((threadIdx.x & 63) == 0) red[threadIdx.x >> 6] = v;
    __syncthreads();
    float tot = 0.f;
    #pragma unroll
    for (int i = 0; i < 16; i++) tot += red[i];
    nx[b * D_DIM + d] = gx / (tot * (1.f / (float)D_DIM) + 1e-6f);
}

// ---------------------------------------------------------------------------
// frh = fr * (gamma*(h*nx) + beta + h) -> bf16
// ---------------------------------------------------------------------------
__global__ void __launch_bounds__(256)
frh_kernel(const float* __restrict__ h, const bf16_t* __restrict__ fr,
           const float* __restrict__ nx, const float* __restrict__ gamma,
           const float* __restrict__ beta, bf16_t* __restrict__ outp)
{
    const size_t gid = (size_t)blockIdx.x * 256 + threadIdx.x;
    const size_t i4 = gid * 4;
    const int d = (int)(i4 & (D_DIM - 1));
    const int b = (int)(i4 >> 21);     // T*D = 2^21
    f32x4 hv = *(const f32x4*)(h + i4);
    bf16x4 fv = *(const bf16x4*)(fr + i4);
    f32x4 nv = *(const f32x4*)(nx + (size_t)b * D_DIM + d);
    f32x4 gm = *(const f32x4*)(gamma + d);
    f32x4 bt = *(const f32x4*)(beta + d);
    bf16x4 o;
    #pragma unroll
    for (int e = 0; e < 4; e++) {
        const float hh = hv[e];
        const float val = gm[e] * (hh * nv[e]) + bt[e] + hh;
        o[e] = (bf16_t)((float)fv[e] * val);
    }
    *(bf16x4*)(outp + i4) = o;
}

// ---------------------------------------------------------------------------
extern "C" void kernel_launch(void* const* d_in, const int* in_sizes, int n_in,
                              void* d_out, int out_size, void* d_ws, size_t ws_size,
                              hipStream_t stream)
{
    (void)in_sizes; (void)n_in; (void)out_size; (void)ws_size;

    const float* x      = (const float*)d_in[0];
    const float* state0 = (const float*)d_in[1];
    const float* ln1_w  = (const float*)d_in[2];
    const float* ln1_b  = (const float*)d_in[3];
    const float* ln2_w  = (const float*)d_in[4];
    const float* ln2_b  = (const float*)d_in[5];
    const float* gn_w   = (const float*)d_in[6];
    const float* gn_b   = (const float*)d_in[7];
    const float* grn_g  = (const float*)d_in[8];
    const float* grn_b  = (const float*)d_in[9];
    const float* decay  = (const float*)d_in[10];
    const float* bfk    = (const float*)d_in[20];
    const float* bfv    = (const float*)d_in[22];
    const float* bfr    = (const float*)d_in[24];

    // workspace layout (~216 MB total)
    const size_t WSZ = (size_t)D_DIM * D_DIM;
    float*  F1 = (float*)d_ws;         // k -> u -> states -> h   (fp32, 64MB)
    bf16_t* B0 = (bf16_t*)(F1 + SZ);   // xm -> xx2               (bf16, 32MB)
    bf16_t* B1 = B0 + SZ;              // a -> mixed -> k_ffn
    bf16_t* B2 = B1 + SZ;              // sr=sigmoid(r) -> fr
    bf16_t* B3 = B2 + SZ;              // g -> frh
    bf16_t* WT = B3 + SZ;              // 11 transposed bf16 weights (22MB)
    float*  carry   = (float*)(WT + NW * WSZ);
    float*  inc     = carry + (size_t)B_DIM * CCH * D_DIM;
    float*  partial = inc + (size_t)B_DIM * CCH * D_DIM;
    float*  nxp     = partial + (size_t)B_DIM * GCH * D_DIM;
    float*  ewp     = nxp + (size_t)B_DIM * D_DIM;

    // weight slots: 0 Wr,1 Wk,2 Wv,3 Wa,4 Wb,5 Wg,6 Wout,7 Wfk,8 Wfv,9 Wfr,10 Wffnout
    WList wl;
    const int widx[NW] = {11, 12, 13, 15, 16, 14, 17, 19, 21, 23, 18};
    for (int i = 0; i < NW; i++) wl.w[i] = (const float*)d_in[widx[i]];

    float* out_x  = (float*)d_out;
    float* out_st = out_x + SZ;

    transpose_cvt_kernel<<<dim3(32, 32, NW), dim3(32, 8), 0, stream>>>(wl, WT);
    ew_kernel<<<4, 256, 0, stream>>>(decay, ewp);
    ln_shift_kernel<<<M_DIM, 256, 0, stream>>>(x, ln1_w, ln1_b, B0);

    const int gg = (M_DIM / 128) * (D_DIM / 128);   // 1024 blocks, 1-D XCD-swizzled
    // sr = sigmoid(xm@Wr) [bf16]
    gemm_kernel<1, 0, true,  false><<<gg, 256, 0, stream>>>(B0, WT + 0 * WSZ, B2, nullptr, nullptr);
    // k [fp32]
    gemm_kernel<0, 0, false, false><<<gg, 256, 0, stream>>>(B0, WT + 1 * WSZ, F1, nullptr, nullptr);
    // u = v*k (in-place on F1)
    gemm_kernel<0, 1, false, false><<<gg, 256, 0, stream>>>(B0, WT + 2 * WSZ, F1, nullptr, F1);
    // a [bf16]
    gemm_kernel<0, 0, true,  false><<<gg, 256, 0, stream>>>(B0, WT + 3 * WSZ, B1, nullptr, nullptr);
    // u += b*a
    gemm_kernel<0, 2, false, true ><<<gg, 256, 0, stream>>>(B0, WT + 4 * WSZ, F1, nullptr, B1);
    // g = sigmoid(xm@Wg) [bf16]
    gemm_kernel<1, 0, true,  false><<<gg, 256, 0, stream>>>(B0, WT + 5 * WSZ, B3, nullptr, nullptr);

    scan1_kernel<<<(CCH * B_DIM * D_DIM) / 256, 256, 0, stream>>>(F1, ewp, carry);
    scan2_kernel<<<(B_DIM * D_DIM) / 256, 256, 0, stream>>>(state0, ewp, carry, inc, out_st);
    mixed_kernel<<<M_DIM, 256, 0, stream>>>(F1, inc, ewp, B2, B3, gn_w, gn_b, B1);

    // x2 = x + mixed @ Wout  -> directly into d_out
    gemm_kernel<0, 3, false, false><<<gg, 256, 0, stream>>>(B1, WT + 6 * WSZ, out_x, nullptr, x);
    ln2_kernel<<<M_DIM, 256, 0, stream>>>(out_x, ln2_w, ln2_b, B0);

    // k_ffn = relu^2(xx2@Wfk + bfk) [bf16]; h = k_ffn@Wfv + bfv [fp32];
    // fr = sigmoid(xx2@Wfr + bfr) [bf16]
    gemm_kernel<2, 0, true,  false><<<gg, 256, 0, stream>>>(B0, WT + 7 * WSZ, B1, bfk, nullptr);
    gemm_kernel<0, 0, false, false><<<gg, 256, 0, stream>>>(B1, WT + 8 * WSZ, F1, bfv, nullptr);
    gemm_kernel<1, 0, true,  false><<<gg, 256, 0, stream>>>(B0, WT + 9 * WSZ, B2, bfr, nullptr);

    grn1_kernel<<<B_DIM * GCH, 256, 0, stream>>>(F1, partial);
    grn2_kernel<<<B_DIM, 1024, 0, stream>>>(partial, nxp);
    frh_kernel<<<M_DIM, 256, 0, stream>>>(F1, B2, nxp, grn_g, grn_b, B3);

    // out = x2 + frh @ Wffnout  (in-place accumulate into d_out)
    gemm_kernel<0, 3, false, false><<<gg, 256, 0, stream>>>(B3, WT + 10 * WSZ, out_x, nullptr, out_x);
}